// Round 13
// baseline (94.579 us; speedup 1.0000x reference)
//
#include <hip/hip_runtime.h>

#define BB 8
#define CL 4096
#define QL 512
#define DD 256

typedef unsigned short u16;
typedef unsigned char u8;
typedef long long i64;
typedef unsigned int u32;
typedef float f32x4 __attribute__((ext_vector_type(4)));
typedef short s16x8 __attribute__((ext_vector_type(8)));
typedef unsigned int u32x4 __attribute__((ext_vector_type(4)));

static __device__ __forceinline__ u16 f2bf(float x) {
  unsigned int u = __float_as_uint(x);
  u += 0x7FFFu + ((u >> 16) & 1u);
  return (u16)(u >> 16);
}
static __device__ __forceinline__ float bf2f(u16 h) {
  return __uint_as_float(((unsigned int)h) << 16);
}

// ---------------- K0: prep q (bf16 row-major, fp8 transposed, qw dots) ----
__global__ __launch_bounds__(256) void prep_q_k(
    const float* __restrict__ q, const float* __restrict__ w,
    u16* __restrict__ qbf, u8* __restrict__ qt8, float* __restrict__ qw_g)
{
  __shared__ u16 qs[8][256];
  __shared__ float red[8][32];
  int blk = blockIdx.x;
  int b = blk & 7;
  int j0 = (blk >> 3) * 8;
  int t = threadIdx.x;
  int r = t >> 5;
  int cs = (t & 31) * 8;

  const float* qrow = q + ((size_t)(b * QL + j0 + r)) * DD + cs;
  float4 v0 = *(const float4*)(qrow);
  float4 v1 = *(const float4*)(qrow + 4);
  float4 w0 = *(const float4*)(w + cs);       // w_q
  float4 w1 = *(const float4*)(w + cs + 4);
  float pw = v0.x*w0.x + v0.y*w0.y + v0.z*w0.z + v0.w*w0.w
           + v1.x*w1.x + v1.y*w1.y + v1.z*w1.z + v1.w*w1.w;

  union { u16 u[8]; uint4 v; } pk;
  pk.u[0]=f2bf(v0.x); pk.u[1]=f2bf(v0.y); pk.u[2]=f2bf(v0.z); pk.u[3]=f2bf(v0.w);
  pk.u[4]=f2bf(v1.x); pk.u[5]=f2bf(v1.y); pk.u[6]=f2bf(v1.z); pk.u[7]=f2bf(v1.w);

  *(uint4*)(qbf + ((size_t)(b * QL + j0 + r)) * DD + cs) = pk.v;
  *(uint4*)(&qs[r][cs]) = pk.v;
  red[r][t & 31] = pw;
  __syncthreads();

  if (t < 8) {
    float s = 0.f;
    #pragma unroll
    for (int k = 0; k < 32; ++k) s += red[t][k];
    qw_g[b * QL + j0 + t] = s;
  }

  // transpose: thread t owns column d = t; 8 j's -> 8 fp8 packed in 2 dwords
  int d = t;
  float f[8];
  #pragma unroll
  for (int jj = 0; jj < 8; ++jj) f[jj] = bf2f(qs[jj][d]);
  unsigned int lo = __builtin_amdgcn_cvt_pk_fp8_f32(f[0], f[1], 0u, false);
  lo = __builtin_amdgcn_cvt_pk_fp8_f32(f[2], f[3], lo, true);
  unsigned int hi = __builtin_amdgcn_cvt_pk_fp8_f32(f[4], f[5], 0u, false);
  hi = __builtin_amdgcn_cvt_pk_fp8_f32(f[6], f[7], hi, true);
  *(unsigned int*)(qt8 + ((size_t)(b * DD + d)) * QL + j0) = lo;
  *(unsigned int*)(qt8 + ((size_t)(b * DD + d)) * QL + j0 + 4) = hi;
}

// ---------------- K1: 64-row tile; cooperatively-staged q panels ----------
// GEMM1: q staged in 32-j panels (16 KB, dbuf) shared by 8 waves (4 i-groups
// x 2 j-subgroups); cm (c*w_m) held in REGISTERS as B-frags. Per-panel fused
// exp + packed fp8 P-write. 1 barrier/panel. GEMM2 fp8 as R12.
__global__ __launch_bounds__(512, 4) void attn_main_k(
    const float* __restrict__ c, const float* __restrict__ w,
    const u16* __restrict__ qbf, const u8* __restrict__ qt8,
    const float* __restrict__ qw_g,
    float* __restrict__ pm_g, float* __restrict__ z_g,
    float* __restrict__ part_g, float* __restrict__ out)
{
  __shared__ u16 qpan[2][32 * 256];   // 16 KB x2 panel double-buffer
  __shared__ u8  P[64 * 512];         // exp(S') fp8, swizzled (32 KB)
  __shared__ float qw_s[QL];
  __shared__ float cw_s[64];
  __shared__ float red_m[64][2];      // [row][jw]
  __shared__ float red_z[64][2];

  int t = threadIdx.x;
  int blk = blockIdx.x;
  int b = blk & 7;
  int tile = blk >> 3;                // 0..63
  int it0 = tile * 64;

  int wv = t >> 6;                    // 0..7
  int ln = t & 63;
  int lr = ln & 15;
  int lg = ln >> 4;
  int iw = wv >> 1;                   // i-group 0..3 (16 rows each)
  int jw = wv & 1;                    // j-subgroup 0..1

  // ---- panel staging geometry (thread covers 2x16B chunks per panel) ----
  int clm = ln & 31;
  int jlA = 2 * wv + (ln >> 5);       // rows 0..15
  int jlB = jlA + 16;                 // rows 16..31
  int wA = jlA * 256 + ((clm ^ (jlA & 7)) * 8);   // swizzled LDS u16 idx
  int wB = jlB * 256 + ((clm ^ (jlB & 7)) * 8);
  const u16* qsrc = qbf + (size_t)b * QL * DD;

  // issue panel-0 loads (land during cm prologue)
  u32x4 sA = *(const u32x4*)(qsrc + (size_t)jlA * 256 + clm * 8);
  u32x4 sB = *(const u32x4*)(qsrc + (size_t)jlB * 256 + clm * 8);

  // ---- cm prologue: wave's 16 c-rows -> registers (B-frag layout) ----
  // lane (lr,lg): c-row it0+iw*16+lr, k-chunks lg*8 + kk*32
  s16x8 cmf[8];
  float pcw = 0.f;
  {
    const float* crow = c + (size_t)(b * CL + it0 + iw * 16 + lr) * DD + lg * 8;
    const float* wc = w + DD + lg * 8;
    const float* wm = w + 2 * DD + lg * 8;
    #pragma unroll
    for (int kk = 0; kk < 8; ++kk) {
      f32x4 c0  = *(const f32x4*)(crow + kk * 32);
      f32x4 c1  = *(const f32x4*)(crow + kk * 32 + 4);
      f32x4 wc0 = *(const f32x4*)(wc + kk * 32);
      f32x4 wc1 = *(const f32x4*)(wc + kk * 32 + 4);
      f32x4 wm0 = *(const f32x4*)(wm + kk * 32);
      f32x4 wm1 = *(const f32x4*)(wm + kk * 32 + 4);
      pcw += c0[0]*wc0[0] + c0[1]*wc0[1] + c0[2]*wc0[2] + c0[3]*wc0[3]
           + c1[0]*wc1[0] + c1[1]*wc1[1] + c1[2]*wc1[2] + c1[3]*wc1[3];
      union { u16 u[8]; s16x8 v; } pk;
      pk.u[0] = f2bf(c0[0]*wm0[0]); pk.u[1] = f2bf(c0[1]*wm0[1]);
      pk.u[2] = f2bf(c0[2]*wm0[2]); pk.u[3] = f2bf(c0[3]*wm0[3]);
      pk.u[4] = f2bf(c1[0]*wm1[0]); pk.u[5] = f2bf(c1[1]*wm1[1]);
      pk.u[6] = f2bf(c1[2]*wm1[2]); pk.u[7] = f2bf(c1[3]*wm1[3]);
      cmf[kk] = pk.v;
    }
  }
  pcw += __shfl_xor(pcw, 16);
  pcw += __shfl_xor(pcw, 32);
  if (jw == 0 && lg == 0) cw_s[iw * 16 + lr] = pcw;
  qw_s[t] = qw_g[b * QL + t];

  // ---- GEMM1 panel loop: mfma(q_panel_Afrag, cm_Bfrag) ----
  // D[j][i]: i = lr (wave rows iw*16+lr), j = p*32 + jw*16 + lg*4 + rr
  float zacc = 0.f, macc = -1e30f;
  int jrow = jw * 16 + lr;
  int aoff = jrow * 256;
  int aswz = (jrow & 7) << 3;
  int pi = iw * 16 + lr;              // P row owned for writes
  int piswz = (pi & 7) << 3;

  for (int p = 0; p < 16; ++p) {
    u16* qb = &qpan[p & 1][0];
    *(u32x4*)(qb + wA) = sA;          // write staged panel p
    *(u32x4*)(qb + wB) = sB;
    __syncthreads();                  // panel visible; old buf reads done
    if (p < 15) {                     // prefetch panel p+1 (lands under MFMA)
      sA = *(const u32x4*)(qsrc + (size_t)((p + 1) * 32 + jlA) * 256 + clm * 8);
      sB = *(const u32x4*)(qsrc + (size_t)((p + 1) * 32 + jlB) * 256 + clm * 8);
    }
    f32x4 acc = (f32x4){0.f, 0.f, 0.f, 0.f};
    #pragma unroll
    for (int kk = 0; kk < 8; ++kk) {
      s16x8 aq = *(const s16x8*)(qb + aoff + ((kk * 32 + lg * 8) ^ aswz));
      acc = __builtin_amdgcn_mfma_f32_16x16x32_bf16(aq, cmf[kk], acc, 0, 0, 0);
    }
    f32x4 qq = *(const f32x4*)(&qw_s[p * 32 + jw * 16 + lg * 4]);
    float s0 = acc[0] + qq[0], s1 = acc[1] + qq[1];
    float s2 = acc[2] + qq[2], s3 = acc[3] + qq[3];
    macc = fmaxf(macc, fmaxf(fmaxf(s0, s1), fmaxf(s2, s3)));
    float e0 = __expf(s0), e1 = __expf(s1), e2 = __expf(s2), e3 = __expf(s3);
    zacc += (e0 + e1) + (e2 + e3);
    u32 p4 = __builtin_amdgcn_cvt_pk_fp8_f32(e0, e1, 0u, false);
    p4 = __builtin_amdgcn_cvt_pk_fp8_f32(e2, e3, p4, true);
    int pj = p * 32 + jw * 16 + lg * 4;
    *(u32*)(P + pi * 512 + (pj ^ piswz)) = p4;
  }

  // ---- per-row z/max combine (lg reduce, jw pairs via LDS) ----
  zacc += __shfl_xor(zacc, 16);
  zacc += __shfl_xor(zacc, 32);
  macc = fmaxf(macc, __shfl_xor(macc, 16));
  macc = fmaxf(macc, __shfl_xor(macc, 32));
  if (lg == 0) { red_z[pi][jw] = zacc; red_m[pi][jw] = macc; }
  __syncthreads();   // P + red visible

  // ---- GEMM2 (fp8, swapped): o2[m][n] = c2q[i=m*16+lr][d=dc+n*16+lg*4..] -
  f32x4 o2[4][2];
  #pragma unroll
  for (int m = 0; m < 4; ++m)
    #pragma unroll
    for (int n = 0; n < 2; ++n) o2[m][n] = (f32x4){0.f, 0.f, 0.f, 0.f};

  int dc = wv * 32;
  const u8* qt = qt8 + (size_t)b * DD * QL + (size_t)(dc + lr) * QL + lg * 8;
  #pragma unroll
  for (int kk = 0; kk < 16; ++kk) {
    i64 bv0 = *(const i64*)(qt + kk * 32);
    i64 bv1 = *(const i64*)(qt + (size_t)16 * QL + kk * 32);
    i64 pa[4];
    #pragma unroll
    for (int m = 0; m < 4; ++m) {
      int pr = m * 16 + lr;
      pa[m] = *(const i64*)(P + pr * 512 + ((kk * 32 + lg * 8) ^ ((pr & 7) << 3)));
    }
    #pragma unroll
    for (int m = 0; m < 4; ++m) {
      o2[m][0] = __builtin_amdgcn_mfma_f32_16x16x32_fp8_fp8(bv0, pa[m], o2[m][0], 0, 0, 0);
      o2[m][1] = __builtin_amdgcn_mfma_f32_16x16x32_fp8_fp8(bv1, pa[m], o2[m][1], 0, 0, 0);
    }
  }

  // ---- per-thread row stats ----
  float invz[4], wgt[4], mt[4];
  float pmx = -1e30f;
  #pragma unroll
  for (int m = 0; m < 4; ++m) {
    int i = m * 16 + lr;
    mt[m] = cw_s[i] + fmaxf(red_m[i][0], red_m[i][1]);
    pmx = fmaxf(pmx, mt[m]);
    invz[m] = 1.0f / (red_z[i][0] + red_z[i][1]);
  }
  pmx = fmaxf(pmx, __shfl_xor(pmx, 1));
  pmx = fmaxf(pmx, __shfl_xor(pmx, 2));
  pmx = fmaxf(pmx, __shfl_xor(pmx, 4));
  pmx = fmaxf(pmx, __shfl_xor(pmx, 8));
  float zs = 0.f;
  #pragma unroll
  for (int m = 0; m < 4; ++m) { wgt[m] = __expf(mt[m] - pmx); zs += wgt[m]; }
  zs += __shfl_xor(zs, 1);
  zs += __shfl_xor(zs, 2);
  zs += __shfl_xor(zs, 4);
  zs += __shfl_xor(zs, 8);
  if (t == 0) { pm_g[b * 64 + tile] = pmx; z_g[b * 64 + tile] = zs; }

  // ---- epilogue: float4 seg0 (c), seg1 (c2q), seg2 (c*c2q), q2c partial --
  const float* cb = c + ((size_t)(b * CL + it0)) * DD;
  float* ob = out + ((size_t)(b * CL + it0)) * (4 * DD);
  #pragma unroll
  for (int n = 0; n < 2; ++n) {
    int d4 = dc + n * 16 + lg * 4;
    f32x4 psum = (f32x4){0.f, 0.f, 0.f, 0.f};
    #pragma unroll
    for (int m = 0; m < 4; ++m) {
      int i = m * 16 + lr;
      f32x4 cv = *(const f32x4*)(cb + (size_t)i * DD + d4);
      f32x4 c2q = o2[m][n] * invz[m];
      float* orow = ob + (size_t)i * (4 * DD);
      *(f32x4*)(orow + d4) = cv;                 // segment 0
      *(f32x4*)(orow + DD + d4) = c2q;           // segment 1
      *(f32x4*)(orow + 2 * DD + d4) = cv * c2q;  // segment 2
      psum += wgt[m] * cv;
    }
    #pragma unroll
    for (int j = 0; j < 4; ++j) {
      psum[j] += __shfl_xor(psum[j], 1);
      psum[j] += __shfl_xor(psum[j], 2);
      psum[j] += __shfl_xor(psum[j], 4);
      psum[j] += __shfl_xor(psum[j], 8);
    }
    if (lr == 0)
      *(f32x4*)(part_g + ((size_t)(b * 64 + tile)) * DD + d4) = psum;
  }
}

// ---------------- K2: fused q2c reduce + segment 3 (float4) ---------------
__global__ __launch_bounds__(256) void q2c_seg3_k(
    const float* __restrict__ c,
    const float* __restrict__ pm_g, const float* __restrict__ z_g,
    const float* __restrict__ part_g, float* __restrict__ out)
{
  __shared__ float wk[64];
  int blk = blockIdx.x;
  int b = blk & 7;
  int chunk = blk >> 3;          // 0..31, each 128 rows
  int t = threadIdx.x;

  if (t < 64) {
    float p = pm_g[b * 64 + t];
    float m = p;
    #pragma unroll
    for (int o = 1; o < 64; o <<= 1) m = fmaxf(m, __shfl_xor(m, o));
    float ew = __expf(p - m);
    float zi = ew * z_g[b * 64 + t];
    float s = zi;
    #pragma unroll
    for (int o = 1; o < 64; o <<= 1) s += __shfl_xor(s, o);
    wk[t] = ew / s;
  }
  __syncthreads();

  int c4 = (t & 63) * 4;
  f32x4 g = (f32x4){0.f, 0.f, 0.f, 0.f};
  #pragma unroll 8
  for (int k = 0; k < 64; ++k)
    g += wk[k] * *(const f32x4*)(part_g + ((size_t)(b * 64 + k)) * DD + c4);

  int r0 = chunk * 128 + (t >> 6);
  for (int it = 0; it < 32; ++it) {
    int row = r0 + it * 4;
    f32x4 cv = *(const f32x4*)(c + ((size_t)(b * CL + row)) * DD + c4);
    *(f32x4*)(out + ((size_t)(b * CL + row)) * (4 * DD) + 3 * DD + c4) = cv * g;
  }
}

extern "C" void kernel_launch(void* const* d_in, const int* in_sizes, int n_in,
                              void* d_out, int out_size, void* d_ws, size_t ws_size,
                              hipStream_t stream) {
  const float* q = (const float*)d_in[0];
  const float* c = (const float*)d_in[1];
  const float* w = (const float*)d_in[2];
  float* out = (float*)d_out;
  char* ws = (char*)d_ws;

  u16*   qbf  = (u16*)(ws);                    // 2,097,152 B
  u8*    qt8  = (u8*)(ws + 2097152);           // 1,048,576 B
  float* qw   = (float*)(ws + 3145728);        //    16,384 B
  float* pm   = (float*)(ws + 3162112);        //     2,048 B
  float* zb   = (float*)(ws + 3164160);        //     2,048 B
  float* part = (float*)(ws + 3166208);        //   524,288 B

  prep_q_k<<<512, 256, 0, stream>>>(q, w, qbf, qt8, qw);
  attn_main_k<<<512, 512, 0, stream>>>(c, w, qbf, qt8, qw, pm, zb, part, out);
  q2c_seg3_k<<<256, 256, 0, stream>>>(c, pm, zb, part, out);
}